// Round 1
// baseline (1064.012 us; speedup 1.0000x reference)
//
#include <hip/hip_runtime.h>

#define HID 32
#define NATOMS 250000
#define NPAIRS 4000000
#define MAXNEI 16
#define NMOL 2000
#define MAXATOMS 128
#define FEAT 8
#define GBLK 128

__device__ __forceinline__ float sigmoidf_(float x) {
    return 1.0f / (1.0f + __expf(-x));
}
__device__ __forceinline__ float tanhfast_(float x) {
    float e = __expf(2.0f * x);
    return 1.0f - 2.0f / (e + 1.0f);
}

// h0 = tf @ W_i_a ; agg0 = (sum_n relu(edge_in[idx_n-1] @ W_i_b)) @ W_h
// 32 lanes per atom (lane = output channel j), 8 atoms per 256-thread block.
__global__ __launch_bounds__(256) void k_init(
        const float* __restrict__ tf, const float* __restrict__ fdg,
        const float* __restrict__ rij, const int* __restrict__ bsc,
        const float* __restrict__ Wia, const float* __restrict__ Wib,
        const float* __restrict__ Wh,
        float* __restrict__ h, float* __restrict__ agg) {
    int gid = blockIdx.x * (blockDim.x >> 5) + (threadIdx.x >> 5);
    int j = threadIdx.x & 31;
    if (gid >= NATOMS) return;

    // h0[gid][j]
    float hv = 0.f;
#pragma unroll
    for (int k = 0; k < FEAT; k++) hv = fmaf(tf[gid * FEAT + k], Wia[k * HID + j], hv);

    // preload W_i_b column j (9 regs)
    float wib[9];
#pragma unroll
    for (int k = 0; k < 9; k++) wib[k] = Wib[k * HID + j];

    float aggE = 0.f;
    for (int n = 0; n < MAXNEI; n++) {
        int idx = bsc[gid * MAXNEI + n];
        if (idx > 0) {
            int p = idx - 1;
            float acc = 0.f;
#pragma unroll
            for (int k = 0; k < FEAT; k++) acc = fmaf(fdg[(size_t)p * FEAT + k], wib[k], acc);
            acc = fmaf(rij[p], wib[8], acc);
            aggE += fmaxf(acc, 0.f);
        }
    }
    // agg[gid][j] = sum_k aggE_k * Wh[k][j]  (shuffle broadcast within 32-lane group)
    float out = 0.f;
#pragma unroll
    for (int k = 0; k < HID; k++) {
        float ek = __shfl(aggE, k, 32);
        out = fmaf(ek, Wh[k * HID + j], out);
    }
    h[(size_t)gid * HID + j] = hv;
    agg[(size_t)gid * HID + j] = out;
}

// GRU update, one thread per atom. xh row kept in LDS (runtime-k reads),
// weights read with wave-uniform addresses -> scalar loads.
__global__ __launch_bounds__(GBLK) void k_gru(
        float* __restrict__ h, const float* __restrict__ agg,
        const float* __restrict__ Wz, const float* __restrict__ Wr,
        const float* __restrict__ Whh, const float* __restrict__ bz,
        const float* __restrict__ br, const float* __restrict__ bh) {
    __shared__ float xh[GBLK * 65];
    int tid = threadIdx.x;
    int a = blockIdx.x * GBLK + tid;
    if (a >= NATOMS) return;   // no __syncthreads anywhere -> early return safe
    float* myxh = &xh[tid * 65];

    float hreg[HID];
#pragma unroll
    for (int k = 0; k < HID; k += 4) {
        float4 av = *(const float4*)&agg[(size_t)a * HID + k];
        myxh[k] = av.x; myxh[k + 1] = av.y; myxh[k + 2] = av.z; myxh[k + 3] = av.w;
        float4 hv = *(const float4*)&h[(size_t)a * HID + k];
        hreg[k] = hv.x; hreg[k + 1] = hv.y; hreg[k + 2] = hv.z; hreg[k + 3] = hv.w;
        myxh[32 + k] = hv.x; myxh[33 + k] = hv.y; myxh[34 + k] = hv.z; myxh[35 + k] = hv.w;
    }

    float accz[HID], accr[HID];
#pragma unroll
    for (int j = 0; j < HID; j++) { accz[j] = bz[j]; accr[j] = br[j]; }

    for (int k = 0; k < 2 * HID; k++) {          // runtime k, uniform
        float xk = myxh[k];
#pragma unroll
        for (int j = 0; j < HID; j++) {          // compile-time j
            accz[j] = fmaf(xk, Wz[k * HID + j], accz[j]);
            accr[j] = fmaf(xk, Wr[k * HID + j], accr[j]);
        }
    }

    float z[HID];
#pragma unroll
    for (int j = 0; j < HID; j++) {
        z[j] = sigmoidf_(accz[j]);
        float r = sigmoidf_(accr[j]);
        myxh[32 + j] = r * hreg[j];              // xh2 = [agg, r*h]
    }

    float acch[HID];
#pragma unroll
    for (int j = 0; j < HID; j++) acch[j] = bh[j];
    for (int k = 0; k < 2 * HID; k++) {
        float xk = myxh[k];
#pragma unroll
        for (int j = 0; j < HID; j++) acch[j] = fmaf(xk, Whh[k * HID + j], acch[j]);
    }

#pragma unroll
    for (int j = 0; j < HID; j += 4) {
        float4 o;
        o.x = (1.f - z[j    ]) * hreg[j    ] + z[j    ] * tanhfast_(acch[j    ]);
        o.y = (1.f - z[j + 1]) * hreg[j + 1] + z[j + 1] * tanhfast_(acch[j + 1]);
        o.z = (1.f - z[j + 2]) * hreg[j + 2] + z[j + 2] * tanhfast_(acch[j + 2]);
        o.w = (1.f - z[j + 3]) * hreg[j + 3] + z[j + 3] * tanhfast_(acch[j + 3]);
        *(float4*)&h[(size_t)a * HID + j] = o;
    }
}

// agg = (sum_n h[su[p]] + h[sul[p]]) @ W_h, 32 lanes per atom.
__global__ __launch_bounds__(256) void k_agg(
        const float* __restrict__ h, const int* __restrict__ bsc,
        const int* __restrict__ su, const int* __restrict__ sul,
        const float* __restrict__ Wh, float* __restrict__ agg) {
    int gid = blockIdx.x * (blockDim.x >> 5) + (threadIdx.x >> 5);
    int j = threadIdx.x & 31;
    if (gid >= NATOMS) return;

    int myidx = 0;
    if (j < MAXNEI) myidx = bsc[gid * MAXNEI + j];

    float aggE = 0.f;
#pragma unroll
    for (int n = 0; n < MAXNEI; n++) {
        int idx = __shfl(myidx, n, 32);
        if (idx > 0) {
            int p = idx - 1;
            int a1 = su[p];
            int a2 = sul[p];
            aggE += h[(size_t)a1 * HID + j] + h[(size_t)a2 * HID + j];
        }
    }
    float out = 0.f;
#pragma unroll
    for (int k = 0; k < HID; k++) {
        float ek = __shfl(aggE, k, 32);
        out = fmaf(ek, Wh[k * HID + j], out);
    }
    agg[(size_t)gid * HID + j] = out;
}

// mol_vecs[m][j] = sum_i (l_scope[m][i] ? h[idx-1][j] : 0)
__global__ __launch_bounds__(256) void k_mol(
        const float* __restrict__ h, const int* __restrict__ lsc,
        float* __restrict__ out) {
    int m = blockIdx.x;
    int g = threadIdx.x >> 5;   // 0..7
    int j = threadIdx.x & 31;
    float acc = 0.f;
    for (int i = g; i < MAXATOMS; i += 8) {
        int idx = lsc[m * MAXATOMS + i];
        if (idx > 0) acc += h[(size_t)(idx - 1) * HID + j];
    }
    __shared__ float red[8][33];
    red[g][j] = acc;
    __syncthreads();
    if (g == 0) {
        float s = red[0][j] + red[1][j] + red[2][j] + red[3][j]
                + red[4][j] + red[5][j] + red[6][j] + red[7][j];
        out[m * HID + j] = s;
    }
}

extern "C" void kernel_launch(void* const* d_in, const int* in_sizes, int n_in,
                              void* d_out, int out_size, void* d_ws, size_t ws_size,
                              hipStream_t stream) {
    (void)in_sizes; (void)n_in; (void)out_size; (void)ws_size;
    const float* tf  = (const float*)d_in[0];
    const float* fdg = (const float*)d_in[1];
    const float* rij = (const float*)d_in[2];
    const int*   bsc = (const int*)d_in[3];
    const int*   lsc = (const int*)d_in[4];
    const int*   su  = (const int*)d_in[5];
    const int*   sul = (const int*)d_in[6];
    const float* Wia = (const float*)d_in[7];
    const float* Wib = (const float*)d_in[8];
    const float* Wh  = (const float*)d_in[9];
    const float* gWz = (const float*)d_in[10];
    const float* gWr = (const float*)d_in[11];
    const float* gWh = (const float*)d_in[12];
    const float* gbz = (const float*)d_in[13];
    const float* gbr = (const float*)d_in[14];
    const float* gbh = (const float*)d_in[15];
    float* out = (float*)d_out;

    float* h   = (float*)d_ws;                       // 32 MB
    float* agg = h + (size_t)NATOMS * HID;           // 32 MB

    dim3 agrid((NATOMS + 7) / 8);
    k_init<<<agrid, 256, 0, stream>>>(tf, fdg, rij, bsc, Wia, Wib, Wh, h, agg);

    for (int d = 0; d < 3; d++) {
        k_gru<<<(NATOMS + GBLK - 1) / GBLK, GBLK, 0, stream>>>(
            h, agg, gWz + d * 2 * HID * HID, gWr + d * 2 * HID * HID,
            gWh + d * 2 * HID * HID, gbz + d * HID, gbr + d * HID, gbh + d * HID);
        if (d < 2) {
            k_agg<<<agrid, 256, 0, stream>>>(h, bsc, su, sul, Wh, agg);
        }
    }
    k_mol<<<NMOL, 256, 0, stream>>>(h, lsc, out);
}